// Round 3
// baseline (454.290 us; speedup 1.0000x reference)
//
#include <hip/hip_runtime.h>
#include <hip/hip_bf16.h>
#include <math.h>

// ---------------- graph structure ----------------

__global__ void count_indeg(const int* __restrict__ dst, int e, int* __restrict__ indeg) {
    int i = blockIdx.x * blockDim.x + threadIdx.x;
    if (i < e) atomicAdd(&indeg[dst[i]], 1);
}

// fused setup: dinv + ranges + nodeW table (i < n)  |  weight fake-quant (i < nW)
__global__ void setup_misc(const int* __restrict__ indeg, float* __restrict__ dinv,
                           int* __restrict__ start, int* __restrict__ cursor,
                           int* __restrict__ counter,
                           const float* __restrict__ g2, const float* __restrict__ g3,
                           float4* __restrict__ nodeW, int n,
                           const float* __restrict__ W1, const float* __restrict__ a1,
                           const float* __restrict__ W2, const float* __restrict__ a2,
                           const float* __restrict__ W3, const float* __restrict__ a3,
                           float* __restrict__ w1q, float* __restrict__ w2q,
                           float* __restrict__ w3q, int n1, int n2, int n3) {
    int i = blockIdx.x * blockDim.x + threadIdx.x;
    if (i < n) {
        int d = indeg[i];
        float ds = 1.0f / sqrtf((float)(d + 1));
        dinv[i] = ds;
        nodeW[i] = make_float4(ds, ds * g2[i], ds * g3[i], 0.0f);
        int s = atomicAdd(counter, d);
        start[i] = s;
        cursor[i] = s;
    }
    const float* w; const float* a; float* o; int k;
    if (i < n1) { w = W1; a = a1; o = w1q; k = i; }
    else if (i < n1 + n2) { w = W2; a = a2; o = w2q; k = i - n1; }
    else if (i < n1 + n2 + n3) { w = W3; a = a3; o = w3q; k = i - n1 - n2; }
    else return;
    float s = a[0];
    float v = w[k] / s;
    v = fminf(fmaxf(v, -8.0f), 7.0f);
    o[k] = rintf(v) * s;   // round-half-even, matches jnp.round
}

// CSR fill + per-edge weight precompute: ew{0,1,2}[p] = dinv[s]*{1,g2[s],g3[s]}*dinv[d]
// Invalid src -> ssrc = dst (safe row), ew = 0: gathers need no validity checks.
__global__ void fill_csr_w(const int* __restrict__ src, const int* __restrict__ dst,
                           int e, int* __restrict__ cursor,
                           const float* __restrict__ nodeWf, const float* __restrict__ dinv,
                           int* __restrict__ ssrc, float* __restrict__ ew0,
                           float* __restrict__ ew1, float* __restrict__ ew2, int n) {
    int i = blockIdx.x * blockDim.x + threadIdx.x;
    if (i >= e) return;
    int s = src[i];
    int d = dst[i];
    int p = atomicAdd(&cursor[d], 1);
    if (p < 0 || p >= e) return;
    float dd = dinv[d];
    if ((unsigned)s < (unsigned)n) {
        ssrc[p] = s;
        ew0[p] = nodeWf[(size_t)s * 4 + 0] * dd;
        ew1[p] = nodeWf[(size_t)s * 4 + 1] * dd;
        ew2[p] = nodeWf[(size_t)s * 4 + 2] * dd;
    } else {
        ssrc[p] = d;
        ew0[p] = 0.f; ew1[p] = 0.f; ew2[p] = 0.f;
    }
}

// ---------------- GEMM 128-col + optional fused BN-stats partials ----------------
// C = A@B + rs*bias, rs = di^2 + colsumS[row] (colsumS already includes di factor).

__global__ __launch_bounds__(256) void gemm128_bias(
        const float* __restrict__ A, const float* __restrict__ B,
        const float* __restrict__ bias,
        const float* __restrict__ dinv, const float* __restrict__ colsumS,
        float* __restrict__ C, float* __restrict__ statsP, int M, int K) {
    __shared__ float sA[16][132];
    __shared__ float sB[16][132];
    int tid = threadIdx.x;
    int rowBase = blockIdx.x * 128;
    int tx = tid & 15;
    int ty = tid >> 4;
    float acc[8][8] = {};

    int aRow = tid >> 1;
    int aK   = (tid & 1) * 8;
    int bK   = tid >> 4;
    int bCol = (tid & 15) * 8;

    for (int k0 = 0; k0 < K; k0 += 16) {
        int gRow = rowBase + aRow;
        if (gRow >= M) gRow = M - 1;
        const float* ap = A + (size_t)gRow * K + k0 + aK;
        float4 a0 = *(const float4*)ap;
        float4 a1 = *(const float4*)(ap + 4);
        sA[aK + 0][aRow] = a0.x;
        sA[aK + 1][aRow] = a0.y;
        sA[aK + 2][aRow] = a0.z;
        sA[aK + 3][aRow] = a0.w;
        sA[aK + 4][aRow] = a1.x;
        sA[aK + 5][aRow] = a1.y;
        sA[aK + 6][aRow] = a1.z;
        sA[aK + 7][aRow] = a1.w;
        const float* bp = B + (size_t)(k0 + bK) * 128 + bCol;
        *(float4*)&sB[bK][bCol]     = *(const float4*)bp;
        *(float4*)&sB[bK][bCol + 4] = *(const float4*)(bp + 4);
        __syncthreads();

#pragma unroll
        for (int kk = 0; kk < 16; ++kk) {
            float4 av0 = *(const float4*)&sA[kk][ty * 8];
            float4 av1 = *(const float4*)&sA[kk][ty * 8 + 4];
            float4 bv0 = *(const float4*)&sB[kk][tx * 4];
            float4 bv1 = *(const float4*)&sB[kk][64 + tx * 4];
            float a[8] = {av0.x, av0.y, av0.z, av0.w, av1.x, av1.y, av1.z, av1.w};
            float b[8] = {bv0.x, bv0.y, bv0.z, bv0.w, bv1.x, bv1.y, bv1.z, bv1.w};
#pragma unroll
            for (int i = 0; i < 8; ++i)
#pragma unroll
                for (int j = 0; j < 8; ++j)
                    acc[i][j] = fmaf(a[i], b[j], acc[i][j]);
        }
        __syncthreads();
    }

    int c0 = tx * 4, c1 = 64 + tx * 4;
    float bb[8];
#pragma unroll
    for (int j = 0; j < 4; ++j) { bb[j] = bias[c0 + j]; bb[4 + j] = bias[c1 + j]; }
    float s1[8] = {}, s2[8] = {};
#pragma unroll
    for (int i = 0; i < 8; ++i) {
        int row = rowBase + ty * 8 + i;
        if (row >= M) continue;
        float rs = 1.0f;
        if (dinv) { float di = dinv[row]; rs = di * di + colsumS[row]; }
        float v[8];
#pragma unroll
        for (int j = 0; j < 8; ++j) {
            v[j] = acc[i][j] + rs * bb[j];
            s1[j] += v[j];
            s2[j] += v[j] * v[j];
        }
        *(float4*)&C[(size_t)row * 128 + c0] = *(float4*)&v[0];
        *(float4*)&C[(size_t)row * 128 + c1] = *(float4*)&v[4];
    }
    if (statsP) {
        float* sp = statsP + (blockIdx.x & 63) * 256;
#pragma unroll
        for (int j = 0; j < 4; ++j) { sA[ty][c0 + j] = s1[j]; sA[ty][c1 + j] = s1[4 + j]; }
        __syncthreads();
        if (tid < 128) {
            float t = 0.f;
#pragma unroll
            for (int k = 0; k < 16; ++k) t += sA[k][tid];
            atomicAdd(&sp[tid], t);
        }
        __syncthreads();
#pragma unroll
        for (int j = 0; j < 4; ++j) { sA[ty][c0 + j] = s2[j]; sA[ty][c1 + j] = s2[4 + j]; }
        __syncthreads();
        if (tid < 128) {
            float t = 0.f;
#pragma unroll
            for (int k = 0; k < 16; ++k) t += sA[k][tid];
            atomicAdd(&sp[128 + tid], t);
        }
    }
}

// ---------------- layer-3 GEMM (N<=64) + fused log_softmax ----------------

__global__ __launch_bounds__(256) void gemm40_softmax(
        const float* __restrict__ A, const float* __restrict__ B,
        const float* __restrict__ bias,
        const float* __restrict__ dinv, const float* __restrict__ colsumS,
        float* __restrict__ out, int M, int N, int K) {
    __shared__ float sA[16][132];
    __shared__ float sB[16][68];
    __shared__ float sOut[128][41];
    int tid = threadIdx.x;
    int rowBase = blockIdx.x * 128;
    int tx = tid & 15;
    int ty = tid >> 4;
    float acc[8][4] = {};

    int aRow = tid >> 1;
    int aK   = (tid & 1) * 8;
    int bK   = tid >> 4;
    int bCol = (tid & 15) * 4;

    for (int k0 = 0; k0 < K; k0 += 16) {
        int gRow = rowBase + aRow;
        if (gRow >= M) gRow = M - 1;
        const float* ap = A + (size_t)gRow * K + k0 + aK;
        float4 a0 = *(const float4*)ap;
        float4 a1 = *(const float4*)(ap + 4);
        sA[aK + 0][aRow] = a0.x;
        sA[aK + 1][aRow] = a0.y;
        sA[aK + 2][aRow] = a0.z;
        sA[aK + 3][aRow] = a0.w;
        sA[aK + 4][aRow] = a1.x;
        sA[aK + 5][aRow] = a1.y;
        sA[aK + 6][aRow] = a1.z;
        sA[aK + 7][aRow] = a1.w;
#pragma unroll
        for (int j = 0; j < 4; ++j) {
            int col = bCol + j;
            sB[bK][col] = (col < N) ? B[(size_t)(k0 + bK) * N + col] : 0.0f;
        }
        __syncthreads();
#pragma unroll
        for (int kk = 0; kk < 16; ++kk) {
            float4 av0 = *(const float4*)&sA[kk][ty * 8];
            float4 av1 = *(const float4*)&sA[kk][ty * 8 + 4];
            float4 bv  = *(const float4*)&sB[kk][tx * 4];
            float a[8] = {av0.x, av0.y, av0.z, av0.w, av1.x, av1.y, av1.z, av1.w};
            float b[4] = {bv.x, bv.y, bv.z, bv.w};
#pragma unroll
            for (int i = 0; i < 8; ++i)
#pragma unroll
                for (int j = 0; j < 4; ++j)
                    acc[i][j] = fmaf(a[i], b[j], acc[i][j]);
        }
        __syncthreads();
    }

    int colOut = tx * 4;
    float bb[4];
#pragma unroll
    for (int j = 0; j < 4; ++j) bb[j] = (colOut + j < N) ? bias[colOut + j] : 0.0f;
#pragma unroll
    for (int i = 0; i < 8; ++i) {
        int rowL = ty * 8 + i;
        int row = rowBase + rowL;
        float rs = 1.0f;
        if (row < M) { float di = dinv[row]; rs = di * di + colsumS[row]; }
#pragma unroll
        for (int j = 0; j < 4; ++j)
            if (colOut + j < N) sOut[rowL][colOut + j] = acc[i][j] + rs * bb[j];
    }
    __syncthreads();
    if (tid < 128) {
        int row = rowBase + tid;
        if (row < M) {
            float mx = -INFINITY;
            for (int c = 0; c < N; ++c) mx = fmaxf(mx, sOut[tid][c]);
            float sm = 0.f;
            for (int c = 0; c < N; ++c) sm += expf(sOut[tid][c] - mx);
            float lg = mx + logf(sm);
            float* op = out + (size_t)row * N;
            for (int c = 0; c < N; ++c) op[c] = sOut[tid][c] - lg;
        }
    }
}

// ---------------- fp32 aggregation (layer 1): one WAVE per node ----------------
// Per edge, all 32 lanes of a slot broadcast-load (ssrc, ew) -> one cache line,
// then gather the 512B row. No shfl, no validity checks (ew=0 for invalid).
// colsumS[node] = sum ew0 (coalesced).

__global__ __launch_bounds__(256) void aggregate128_wave(
        const float* __restrict__ h, const float* __restrict__ dinv,
        const int* __restrict__ start, const int* __restrict__ indeg,
        const int* __restrict__ ssrc, const float* __restrict__ ew,
        float* __restrict__ out, float* __restrict__ colsumS, int n, int E) {
    int node = blockIdx.x * 4 + (threadIdx.x >> 6);
    if (node >= n) return;
    int lane = threadIdx.x & 63;
    int slot = lane >> 5;       // 0..1
    int c4 = (lane & 31) * 4;   // column (floats)
    float di = dinv[node];
    int s0 = start[node];
    int len = indeg[node];
    if (s0 < 0) s0 = 0;
    if (len < 0) len = 0;
    if (s0 + len > E) len = (E - s0 > 0) ? (E - s0) : 0;

    // self-loop row load issued early
    float4 hs = *(const float4*)(h + (size_t)node * 128 + c4);

    // colsum partial: coalesced, each edge once
    float wacc = 0.f;
    for (int t = lane; t < len; t += 64) wacc += ew[s0 + t];

    float4 acc = {0.f, 0.f, 0.f, 0.f};
    int j = slot;
    for (; j + 6 < len; j += 8) {
        int   sa = ssrc[s0 + j];     float wa = ew[s0 + j];
        int   sb = ssrc[s0 + j + 2]; float wb = ew[s0 + j + 2];
        int   sc = ssrc[s0 + j + 4]; float wc = ew[s0 + j + 4];
        int   sd = ssrc[s0 + j + 6]; float wd = ew[s0 + j + 6];
        float4 va = *(const float4*)(h + (size_t)sa * 128 + c4);
        float4 vb = *(const float4*)(h + (size_t)sb * 128 + c4);
        float4 vc = *(const float4*)(h + (size_t)sc * 128 + c4);
        float4 vd = *(const float4*)(h + (size_t)sd * 128 + c4);
        acc.x = fmaf(va.x, wa, acc.x); acc.y = fmaf(va.y, wa, acc.y);
        acc.z = fmaf(va.z, wa, acc.z); acc.w = fmaf(va.w, wa, acc.w);
        acc.x = fmaf(vb.x, wb, acc.x); acc.y = fmaf(vb.y, wb, acc.y);
        acc.z = fmaf(vb.z, wb, acc.z); acc.w = fmaf(vb.w, wb, acc.w);
        acc.x = fmaf(vc.x, wc, acc.x); acc.y = fmaf(vc.y, wc, acc.y);
        acc.z = fmaf(vc.z, wc, acc.z); acc.w = fmaf(vc.w, wc, acc.w);
        acc.x = fmaf(vd.x, wd, acc.x); acc.y = fmaf(vd.y, wd, acc.y);
        acc.z = fmaf(vd.z, wd, acc.z); acc.w = fmaf(vd.w, wd, acc.w);
    }
    for (; j < len; j += 2) {
        int   sa = ssrc[s0 + j];
        float wa = ew[s0 + j];
        float4 va = *(const float4*)(h + (size_t)sa * 128 + c4);
        acc.x = fmaf(va.x, wa, acc.x); acc.y = fmaf(va.y, wa, acc.y);
        acc.z = fmaf(va.z, wa, acc.z); acc.w = fmaf(va.w, wa, acc.w);
    }
#pragma unroll
    for (int o = 1; o < 64; o <<= 1) wacc += __shfl_xor(wacc, o);
    acc.x += __shfl_xor(acc.x, 32);
    acc.y += __shfl_xor(acc.y, 32);
    acc.z += __shfl_xor(acc.z, 32);
    acc.w += __shfl_xor(acc.w, 32);
    if (lane < 32) {
        float dd = di * di;
        acc.x = fmaf(hs.x, dd, acc.x);
        acc.y = fmaf(hs.y, dd, acc.y);
        acc.z = fmaf(hs.z, dd, acc.z);
        acc.w = fmaf(hs.w, dd, acc.w);
        *(float4*)(out + (size_t)node * 128 + c4) = acc;
        if (lane == 0) colsumS[node] = wacc;
    }
}

// ---------------- u8 aggregation (layers 2,3): one WAVE per node ----------------
// Same broadcast-load structure; weight precomputed in ew (incl. g scale).

__device__ __forceinline__ void unpack_fma(float* acc, uint4 v, float w) {
    acc[0]  = fmaf((float)(v.x & 255), w, acc[0]);
    acc[1]  = fmaf((float)((v.x >> 8) & 255), w, acc[1]);
    acc[2]  = fmaf((float)((v.x >> 16) & 255), w, acc[2]);
    acc[3]  = fmaf((float)(v.x >> 24), w, acc[3]);
    acc[4]  = fmaf((float)(v.y & 255), w, acc[4]);
    acc[5]  = fmaf((float)((v.y >> 8) & 255), w, acc[5]);
    acc[6]  = fmaf((float)((v.y >> 16) & 255), w, acc[6]);
    acc[7]  = fmaf((float)(v.y >> 24), w, acc[7]);
    acc[8]  = fmaf((float)(v.z & 255), w, acc[8]);
    acc[9]  = fmaf((float)((v.z >> 8) & 255), w, acc[9]);
    acc[10] = fmaf((float)((v.z >> 16) & 255), w, acc[10]);
    acc[11] = fmaf((float)(v.z >> 24), w, acc[11]);
    acc[12] = fmaf((float)(v.w & 255), w, acc[12]);
    acc[13] = fmaf((float)((v.w >> 8) & 255), w, acc[13]);
    acc[14] = fmaf((float)((v.w >> 16) & 255), w, acc[14]);
    acc[15] = fmaf((float)(v.w >> 24), w, acc[15]);
}

__global__ __launch_bounds__(256) void aggregate_q8_wave(
        const unsigned char* __restrict__ q, const float* __restrict__ dinv,
        const float* __restrict__ gscale,
        const int* __restrict__ start, const int* __restrict__ indeg,
        const int* __restrict__ ssrc, const float* __restrict__ ew,
        float* __restrict__ out, int n, int E) {
    int node = blockIdx.x * 4 + (threadIdx.x >> 6);
    if (node >= n) return;
    int lane = threadIdx.x & 63;
    int slot = lane >> 3;      // 0..7
    int sl   = lane & 7;       // covers bytes sl*16..sl*16+15
    float di = dinv[node];
    int s0 = start[node];
    int len = indeg[node];
    if (s0 < 0) s0 = 0;
    if (len < 0) len = 0;
    if (s0 + len > E) len = (E - s0 > 0) ? (E - s0) : 0;

    float acc[16] = {};
    int j = slot;
    for (; j + 8 < len; j += 16) {
        int   sa = ssrc[s0 + j];     float wa = ew[s0 + j];
        int   sb = ssrc[s0 + j + 8]; float wb = ew[s0 + j + 8];
        uint4 va = *(const uint4*)(q + (size_t)sa * 128 + sl * 16);
        uint4 vb = *(const uint4*)(q + (size_t)sb * 128 + sl * 16);
        unpack_fma(acc, va, wa);
        unpack_fma(acc, vb, wb);
    }
    if (j < len) {
        int   sa = ssrc[s0 + j];
        float wa = ew[s0 + j];
        uint4 va = *(const uint4*)(q + (size_t)sa * 128 + sl * 16);
        unpack_fma(acc, va, wa);
    }
#pragma unroll
    for (int o = 8; o < 64; o <<= 1) {
#pragma unroll
        for (int k = 0; k < 16; ++k) acc[k] += __shfl_xor(acc[k], o);
    }
    if (slot == 0) {
        uint4 vs = *(const uint4*)(q + (size_t)node * 128 + sl * 16);
        unpack_fma(acc, vs, gscale[node] * di * di);   // self loop
        float* op = out + (size_t)node * 128 + sl * 16;
        *(float4*)(op + 0)  = *(float4*)&acc[0];
        *(float4*)(op + 4)  = *(float4*)&acc[4];
        *(float4*)(op + 8)  = *(float4*)&acc[8];
        *(float4*)(op + 12) = *(float4*)&acc[12];
    }
}

// ---------------- BN finalize: 64 partial copies -> per-column scale/shift ----------------
// After: statsP[c] = a (= g/sqrt(var+eps)), statsP[128+c] = bp (= b - mean*a)

__global__ void bn_finalize(float* __restrict__ statsP,
                            const float* __restrict__ g, const float* __restrict__ b,
                            int n) {
    __shared__ float sh[256];
    int t = threadIdx.x;   // 256
    float s = 0.f;
    for (int k = 0; k < 64; ++k) s += statsP[k * 256 + t];
    sh[t] = s;
    __syncthreads();
    if (t < 128) {
        float m  = sh[t] / (float)n;
        float vr = sh[128 + t] / (float)n - m * m;
        float a  = g[t] * (1.0f / sqrtf(vr + 1e-5f));
        statsP[t]       = a;
        statsP[128 + t] = b[t] - m * a;
    }
}

// BN affine (precomputed a,bp) + ReLU + 4-bit fake-quant -> u8
__global__ void bn_apply_quant_u8(const float* __restrict__ x,
                                  const float* __restrict__ ab,
                                  const float* __restrict__ gs,
                                  unsigned char* __restrict__ out, int n) {
    int idx = blockIdx.x * blockDim.x + threadIdx.x;
    if (idx >= n * 128) return;
    int c = idx & 127;
    int r = idx >> 7;
    float v = ab[c] * x[idx] + ab[128 + c];
    v = fmaxf(v, 0.0f);
    float qv = fminf(fmaxf(v / gs[r], 0.0f), 15.0f);
    out[idx] = (unsigned char)rintf(qv);   // round-half-even
}

// ---------------- launch ----------------

extern "C" void kernel_launch(void* const* d_in, const int* in_sizes, int n_in,
                              void* d_out, int out_size, void* d_ws, size_t ws_size,
                              hipStream_t stream) {
    float*       xbuf = (float*)d_in[0];          // reused as scratch after layer-1 agg
    const int*   ei   = (const int*)d_in[1];
    const float* W1   = (const float*)d_in[2];
    const float* b1   = (const float*)d_in[3];
    const float* a1   = (const float*)d_in[4];
    const float* W2   = (const float*)d_in[5];
    const float* b2   = (const float*)d_in[6];
    const float* a2   = (const float*)d_in[7];
    const float* g2   = (const float*)d_in[8];
    const float* W3   = (const float*)d_in[9];
    const float* b3   = (const float*)d_in[10];
    const float* a3   = (const float*)d_in[11];
    const float* g3   = (const float*)d_in[12];
    const float* bn1g = (const float*)d_in[13];
    const float* bn1b = (const float*)d_in[14];
    const float* bn2g = (const float*)d_in[15];
    const float* bn2b = (const float*)d_in[16];

    const int n = in_sizes[0] / 128;      // 50000
    const int E = in_sizes[1] / 2;        // 800000
    const int C = in_sizes[9] / 128;      // 40
    const int* src = ei;
    const int* dst = ei + E;

    // ---- workspace layout: zeroed region FIRST ----
    char* wsp = (char*)d_ws;
    size_t off = 0;
    auto take = [&](size_t bytes) -> void* {
        void* p = wsp + off;
        off += (bytes + 255) & ~(size_t)255;
        return p;
    };
    int*   indeg   = (int*)take((size_t)n * 4);
    int*   counter = (int*)take(4);
    float* stats1  = (float*)take(64 * 256 * 4);     // 64 partial copies: sums|sumsq
    float* stats2  = (float*)take(64 * 256 * 4);
    size_t zeroBytes = off;
    int*   startA  = (int*)take((size_t)n * 4);
    int*   cursor  = (int*)take((size_t)n * 4);
    float* dinv    = (float*)take((size_t)n * 4);
    float* colsumS = (float*)take((size_t)n * 4);
    float4* nodeW  = (float4*)take((size_t)n * 16);
    int*   ssrc    = (int*)take((size_t)E * 4);
    float* ew0     = (float*)take((size_t)E * 4);
    float* ew1     = (float*)take((size_t)E * 4);
    float* ew2     = (float*)take((size_t)E * 4);
    float* w1q     = (float*)take(128 * 128 * 4);
    float* w2q     = (float*)take(128 * 128 * 4);
    float* w3q     = (float*)take((size_t)128 * C * 4);
    unsigned char* qbuf = (unsigned char*)take((size_t)n * 128);
    float* hbuf    = (float*)take((size_t)n * 128 * 4);

    float* outF  = (float*)d_out;
    const float* nodeWf = (const float*)nodeW;

    // ---- setup ----
    hipMemsetAsync(d_ws, 0, zeroBytes, stream);
    count_indeg<<<(E + 255) / 256, 256, 0, stream>>>(dst, E, indeg);
    const int nW = 128 * 128 + 128 * 128 + 128 * C;
    int setupN = (n > nW) ? n : nW;
    setup_misc<<<(setupN + 255) / 256, 256, 0, stream>>>(
        indeg, dinv, startA, cursor, counter, g2, g3, nodeW, n,
        W1, a1, W2, a2, W3, a3, w1q, w2q, w3q, 128 * 128, 128 * 128, 128 * C);
    fill_csr_w<<<(E + 255) / 256, 256, 0, stream>>>(src, dst, E, cursor, nodeWf, dinv,
                                                    ssrc, ew0, ew1, ew2, n);

    const int gElem128 = (n * 128 + 255) / 256;
    const int gWave = (n + 3) / 4;
    const int gRow128 = (n + 127) / 128;

    // ---- layer 1: aggregate(x) first (linearity), then GEMM w/ fused rowsum*bias
    //      + fused BN stats ----
    aggregate128_wave<<<gWave, 256, 0, stream>>>(xbuf, dinv, startA, indeg, ssrc, ew0,
                                                 hbuf, colsumS, n, E);
    gemm128_bias<<<gRow128, 256, 0, stream>>>(hbuf, w1q, b1, dinv, colsumS,
                                              xbuf, stats1, n, 128);
    bn_finalize<<<1, 256, 0, stream>>>(stats1, bn1g, bn1b, n);
    bn_apply_quant_u8<<<gElem128, 256, 0, stream>>>(xbuf, stats1, g2, qbuf, n);

    // ---- layer 2: aggregate(q)*W + rowsum*b (stats fused into GEMM) ----
    aggregate_q8_wave<<<gWave, 256, 0, stream>>>(qbuf, dinv, g2, startA, indeg,
                                                 ssrc, ew1, hbuf, n, E);
    gemm128_bias<<<gRow128, 256, 0, stream>>>(hbuf, w2q, b2, dinv, colsumS,
                                              xbuf, stats2, n, 128);
    bn_finalize<<<1, 256, 0, stream>>>(stats2, bn2g, bn2b, n);
    bn_apply_quant_u8<<<gElem128, 256, 0, stream>>>(xbuf, stats2, g3, qbuf, n);

    // ---- layer 3: aggregate(q)*W3 + rowsum*b3, softmax fused ----
    aggregate_q8_wave<<<gWave, 256, 0, stream>>>(qbuf, dinv, g3, startA, indeg,
                                                 ssrc, ew2, hbuf, n, E);
    gemm40_softmax<<<gRow128, 256, 0, stream>>>(hbuf, w3q, b3, dinv, colsumS,
                                                outF, n, C, 128);
}

// Round 5
// 434.373 us; speedup vs baseline: 1.0459x; 1.0459x over previous
//
#include <hip/hip_runtime.h>
#include <hip/hip_bf16.h>
#include <math.h>

// ---------------- graph structure ----------------

__global__ void count_indeg(const int* __restrict__ dst, int e, int* __restrict__ indeg) {
    int i = blockIdx.x * blockDim.x + threadIdx.x;
    if (i < e) atomicAdd(&indeg[dst[i]], 1);
}

// fused setup: dinv + ranges + nodeW table (i < n)  |  weight fake-quant (i < nW)
__global__ void setup_misc(const int* __restrict__ indeg, float* __restrict__ dinv,
                           int* __restrict__ start, int* __restrict__ cursor,
                           int* __restrict__ counter,
                           const float* __restrict__ g2, const float* __restrict__ g3,
                           float4* __restrict__ nodeW, int n,
                           const float* __restrict__ W1, const float* __restrict__ a1,
                           const float* __restrict__ W2, const float* __restrict__ a2,
                           const float* __restrict__ W3, const float* __restrict__ a3,
                           float* __restrict__ w1q, float* __restrict__ w2q,
                           float* __restrict__ w3q, int n1, int n2, int n3) {
    int i = blockIdx.x * blockDim.x + threadIdx.x;
    if (i < n) {
        int d = indeg[i];
        float ds = 1.0f / sqrtf((float)(d + 1));
        dinv[i] = ds;
        nodeW[i] = make_float4(ds, ds * g2[i], ds * g3[i], 0.0f);
        int s = atomicAdd(counter, d);
        start[i] = s;
        cursor[i] = s;
    }
    const float* w; const float* a; float* o; int k;
    if (i < n1) { w = W1; a = a1; o = w1q; k = i; }
    else if (i < n1 + n2) { w = W2; a = a2; o = w2q; k = i - n1; }
    else if (i < n1 + n2 + n3) { w = W3; a = a3; o = w3q; k = i - n1 - n2; }
    else return;
    float s = a[0];
    float v = w[k] / s;
    v = fminf(fmaxf(v, -8.0f), 7.0f);
    o[k] = rintf(v) * s;   // round-half-even, matches jnp.round
}

// CSR fill, AoS edge record: edge[p] = {as_float(src), w0, w1, w2}
// w{0,1,2} = dinv[s]*{1,g2[s],g3[s]}*dinv[d]. ONE scattered 16B store per edge
// (vs 4x4B to separate arrays: 4x fewer dirty cache lines).
// Invalid src -> src = dst (safe row), w = 0: gathers need no validity checks.
__global__ void fill_csr_w(const int* __restrict__ src, const int* __restrict__ dst,
                           int e, int* __restrict__ cursor,
                           const float4* __restrict__ nodeW, const float* __restrict__ dinv,
                           float4* __restrict__ edge, int n) {
    int i = blockIdx.x * blockDim.x + threadIdx.x;
    if (i >= e) return;
    int s = src[i];
    int d = dst[i];
    int p = atomicAdd(&cursor[d], 1);
    if (p < 0 || p >= e) return;
    float dd = dinv[d];
    float4 rec;
    if ((unsigned)s < (unsigned)n) {
        float4 w = nodeW[s];
        rec = make_float4(__int_as_float(s), w.x * dd, w.y * dd, w.z * dd);
    } else {
        rec = make_float4(__int_as_float(d), 0.f, 0.f, 0.f);
    }
    edge[p] = rec;
}

// ---------------- GEMM 128-col + optional fused BN-stats partials ----------------
// C = A@B + rs*bias, rs = di^2 + colsumS[row] (colsumS already includes di factor).

__global__ __launch_bounds__(256) void gemm128_bias(
        const float* __restrict__ A, const float* __restrict__ B,
        const float* __restrict__ bias,
        const float* __restrict__ dinv, const float* __restrict__ colsumS,
        float* __restrict__ C, float* __restrict__ statsP, int M, int K) {
    __shared__ float sA[16][132];
    __shared__ float sB[16][132];
    int tid = threadIdx.x;
    int rowBase = blockIdx.x * 128;
    int tx = tid & 15;
    int ty = tid >> 4;
    float acc[8][8] = {};

    int aRow = tid >> 1;
    int aK   = (tid & 1) * 8;
    int bK   = tid >> 4;
    int bCol = (tid & 15) * 8;

    for (int k0 = 0; k0 < K; k0 += 16) {
        int gRow = rowBase + aRow;
        if (gRow >= M) gRow = M - 1;
        const float* ap = A + (size_t)gRow * K + k0 + aK;
        float4 a0 = *(const float4*)ap;
        float4 a1 = *(const float4*)(ap + 4);
        sA[aK + 0][aRow] = a0.x;
        sA[aK + 1][aRow] = a0.y;
        sA[aK + 2][aRow] = a0.z;
        sA[aK + 3][aRow] = a0.w;
        sA[aK + 4][aRow] = a1.x;
        sA[aK + 5][aRow] = a1.y;
        sA[aK + 6][aRow] = a1.z;
        sA[aK + 7][aRow] = a1.w;
        const float* bp = B + (size_t)(k0 + bK) * 128 + bCol;
        *(float4*)&sB[bK][bCol]     = *(const float4*)bp;
        *(float4*)&sB[bK][bCol + 4] = *(const float4*)(bp + 4);
        __syncthreads();

#pragma unroll
        for (int kk = 0; kk < 16; ++kk) {
            float4 av0 = *(const float4*)&sA[kk][ty * 8];
            float4 av1 = *(const float4*)&sA[kk][ty * 8 + 4];
            float4 bv0 = *(const float4*)&sB[kk][tx * 4];
            float4 bv1 = *(const float4*)&sB[kk][64 + tx * 4];
            float a[8] = {av0.x, av0.y, av0.z, av0.w, av1.x, av1.y, av1.z, av1.w};
            float b[8] = {bv0.x, bv0.y, bv0.z, bv0.w, bv1.x, bv1.y, bv1.z, bv1.w};
#pragma unroll
            for (int i = 0; i < 8; ++i)
#pragma unroll
                for (int j = 0; j < 8; ++j)
                    acc[i][j] = fmaf(a[i], b[j], acc[i][j]);
        }
        __syncthreads();
    }

    int c0 = tx * 4, c1 = 64 + tx * 4;
    float bb[8];
#pragma unroll
    for (int j = 0; j < 4; ++j) { bb[j] = bias[c0 + j]; bb[4 + j] = bias[c1 + j]; }
    float s1[8] = {}, s2[8] = {};
#pragma unroll
    for (int i = 0; i < 8; ++i) {
        int row = rowBase + ty * 8 + i;
        if (row >= M) continue;
        float rs = 1.0f;
        if (dinv) { float di = dinv[row]; rs = di * di + colsumS[row]; }
        float v[8];
#pragma unroll
        for (int j = 0; j < 8; ++j) {
            v[j] = acc[i][j] + rs * bb[j];
            s1[j] += v[j];
            s2[j] += v[j] * v[j];
        }
        *(float4*)&C[(size_t)row * 128 + c0] = *(float4*)&v[0];
        *(float4*)&C[(size_t)row * 128 + c1] = *(float4*)&v[4];
    }
    if (statsP) {
        float* sp = statsP + (blockIdx.x & 63) * 256;
#pragma unroll
        for (int j = 0; j < 4; ++j) { sA[ty][c0 + j] = s1[j]; sA[ty][c1 + j] = s1[4 + j]; }
        __syncthreads();
        if (tid < 128) {
            float t = 0.f;
#pragma unroll
            for (int k = 0; k < 16; ++k) t += sA[k][tid];
            atomicAdd(&sp[tid], t);
        }
        __syncthreads();
#pragma unroll
        for (int j = 0; j < 4; ++j) { sA[ty][c0 + j] = s2[j]; sA[ty][c1 + j] = s2[4 + j]; }
        __syncthreads();
        if (tid < 128) {
            float t = 0.f;
#pragma unroll
            for (int k = 0; k < 16; ++k) t += sA[k][tid];
            atomicAdd(&sp[128 + tid], t);
        }
    }
}

// ---------------- layer-3 GEMM (N<=64) + fused log_softmax ----------------

__global__ __launch_bounds__(256) void gemm40_softmax(
        const float* __restrict__ A, const float* __restrict__ B,
        const float* __restrict__ bias,
        const float* __restrict__ dinv, const float* __restrict__ colsumS,
        float* __restrict__ out, int M, int N, int K) {
    __shared__ float sA[16][132];
    __shared__ float sB[16][68];
    __shared__ float sOut[128][41];
    int tid = threadIdx.x;
    int rowBase = blockIdx.x * 128;
    int tx = tid & 15;
    int ty = tid >> 4;
    float acc[8][4] = {};

    int aRow = tid >> 1;
    int aK   = (tid & 1) * 8;
    int bK   = tid >> 4;
    int bCol = (tid & 15) * 4;

    for (int k0 = 0; k0 < K; k0 += 16) {
        int gRow = rowBase + aRow;
        if (gRow >= M) gRow = M - 1;
        const float* ap = A + (size_t)gRow * K + k0 + aK;
        float4 a0 = *(const float4*)ap;
        float4 a1 = *(const float4*)(ap + 4);
        sA[aK + 0][aRow] = a0.x;
        sA[aK + 1][aRow] = a0.y;
        sA[aK + 2][aRow] = a0.z;
        sA[aK + 3][aRow] = a0.w;
        sA[aK + 4][aRow] = a1.x;
        sA[aK + 5][aRow] = a1.y;
        sA[aK + 6][aRow] = a1.z;
        sA[aK + 7][aRow] = a1.w;
#pragma unroll
        for (int j = 0; j < 4; ++j) {
            int col = bCol + j;
            sB[bK][col] = (col < N) ? B[(size_t)(k0 + bK) * N + col] : 0.0f;
        }
        __syncthreads();
#pragma unroll
        for (int kk = 0; kk < 16; ++kk) {
            float4 av0 = *(const float4*)&sA[kk][ty * 8];
            float4 av1 = *(const float4*)&sA[kk][ty * 8 + 4];
            float4 bv  = *(const float4*)&sB[kk][tx * 4];
            float a[8] = {av0.x, av0.y, av0.z, av0.w, av1.x, av1.y, av1.z, av1.w};
            float b[4] = {bv.x, bv.y, bv.z, bv.w};
#pragma unroll
            for (int i = 0; i < 8; ++i)
#pragma unroll
                for (int j = 0; j < 4; ++j)
                    acc[i][j] = fmaf(a[i], b[j], acc[i][j]);
        }
        __syncthreads();
    }

    int colOut = tx * 4;
    float bb[4];
#pragma unroll
    for (int j = 0; j < 4; ++j) bb[j] = (colOut + j < N) ? bias[colOut + j] : 0.0f;
#pragma unroll
    for (int i = 0; i < 8; ++i) {
        int rowL = ty * 8 + i;
        int row = rowBase + rowL;
        float rs = 1.0f;
        if (row < M) { float di = dinv[row]; rs = di * di + colsumS[row]; }
#pragma unroll
        for (int j = 0; j < 4; ++j)
            if (colOut + j < N) sOut[rowL][colOut + j] = acc[i][j] + rs * bb[j];
    }
    __syncthreads();
    if (tid < 128) {
        int row = rowBase + tid;
        if (row < M) {
            float mx = -INFINITY;
            for (int c = 0; c < N; ++c) mx = fmaxf(mx, sOut[tid][c]);
            float sm = 0.f;
            for (int c = 0; c < N; ++c) sm += expf(sOut[tid][c] - mx);
            float lg = mx + logf(sm);
            float* op = out + (size_t)row * N;
            for (int c = 0; c < N; ++c) op[c] = sOut[tid][c] - lg;
        }
    }
}

// ---------------- fp32 aggregation (layer 1): one WAVE per node ----------------
// Per edge, all 32 lanes of a slot broadcast-load the 16B edge record (one cache
// line), then gather the 512B row. No shfl, no validity checks (w=0 for invalid).
// colsumS[node] = sum edge.y (coalesced).

__global__ __launch_bounds__(256) void aggregate128_wave(
        const float* __restrict__ h, const float* __restrict__ dinv,
        const int* __restrict__ start, const int* __restrict__ indeg,
        const float4* __restrict__ edge,
        float* __restrict__ out, float* __restrict__ colsumS, int n, int E) {
    int node = blockIdx.x * 4 + (threadIdx.x >> 6);
    if (node >= n) return;
    int lane = threadIdx.x & 63;
    int slot = lane >> 5;       // 0..1
    int c4 = (lane & 31) * 4;   // column (floats)
    float di = dinv[node];
    int s0 = start[node];
    int len = indeg[node];
    if (s0 < 0) s0 = 0;
    if (len < 0) len = 0;
    if (s0 + len > E) len = (E - s0 > 0) ? (E - s0) : 0;

    // self-loop row load issued early
    float4 hs = *(const float4*)(h + (size_t)node * 128 + c4);

    // colsum partial: coalesced, each edge once
    float wacc = 0.f;
    for (int t = lane; t < len; t += 64) wacc += edge[s0 + t].y;

    float4 acc = {0.f, 0.f, 0.f, 0.f};
    int j = slot;
    for (; j + 6 < len; j += 8) {
        float4 ea = edge[s0 + j];
        float4 eb = edge[s0 + j + 2];
        float4 ec = edge[s0 + j + 4];
        float4 ed = edge[s0 + j + 6];
        int sa = __float_as_int(ea.x); float wa = ea.y;
        int sb = __float_as_int(eb.x); float wb = eb.y;
        int sc = __float_as_int(ec.x); float wc = ec.y;
        int sd = __float_as_int(ed.x); float wd = ed.y;
        float4 va = *(const float4*)(h + (size_t)sa * 128 + c4);
        float4 vb = *(const float4*)(h + (size_t)sb * 128 + c4);
        float4 vc = *(const float4*)(h + (size_t)sc * 128 + c4);
        float4 vd = *(const float4*)(h + (size_t)sd * 128 + c4);
        acc.x = fmaf(va.x, wa, acc.x); acc.y = fmaf(va.y, wa, acc.y);
        acc.z = fmaf(va.z, wa, acc.z); acc.w = fmaf(va.w, wa, acc.w);
        acc.x = fmaf(vb.x, wb, acc.x); acc.y = fmaf(vb.y, wb, acc.y);
        acc.z = fmaf(vb.z, wb, acc.z); acc.w = fmaf(vb.w, wb, acc.w);
        acc.x = fmaf(vc.x, wc, acc.x); acc.y = fmaf(vc.y, wc, acc.y);
        acc.z = fmaf(vc.z, wc, acc.z); acc.w = fmaf(vc.w, wc, acc.w);
        acc.x = fmaf(vd.x, wd, acc.x); acc.y = fmaf(vd.y, wd, acc.y);
        acc.z = fmaf(vd.z, wd, acc.z); acc.w = fmaf(vd.w, wd, acc.w);
    }
    for (; j < len; j += 2) {
        float4 ea = edge[s0 + j];
        int sa = __float_as_int(ea.x);
        float wa = ea.y;
        float4 va = *(const float4*)(h + (size_t)sa * 128 + c4);
        acc.x = fmaf(va.x, wa, acc.x); acc.y = fmaf(va.y, wa, acc.y);
        acc.z = fmaf(va.z, wa, acc.z); acc.w = fmaf(va.w, wa, acc.w);
    }
#pragma unroll
    for (int o = 1; o < 64; o <<= 1) wacc += __shfl_xor(wacc, o);
    acc.x += __shfl_xor(acc.x, 32);
    acc.y += __shfl_xor(acc.y, 32);
    acc.z += __shfl_xor(acc.z, 32);
    acc.w += __shfl_xor(acc.w, 32);
    if (lane < 32) {
        float dd = di * di;
        acc.x = fmaf(hs.x, dd, acc.x);
        acc.y = fmaf(hs.y, dd, acc.y);
        acc.z = fmaf(hs.z, dd, acc.z);
        acc.w = fmaf(hs.w, dd, acc.w);
        *(float4*)(out + (size_t)node * 128 + c4) = acc;
        if (lane == 0) colsumS[node] = wacc;
    }
}

// ---------------- u8 aggregation (layers 2,3): one WAVE per node ----------------
// Same broadcast-load structure; weight from edge record (z = layer2, w = layer3).

__device__ __forceinline__ void unpack_fma(float* acc, uint4 v, float w) {
    acc[0]  = fmaf((float)(v.x & 255), w, acc[0]);
    acc[1]  = fmaf((float)((v.x >> 8) & 255), w, acc[1]);
    acc[2]  = fmaf((float)((v.x >> 16) & 255), w, acc[2]);
    acc[3]  = fmaf((float)(v.x >> 24), w, acc[3]);
    acc[4]  = fmaf((float)(v.y & 255), w, acc[4]);
    acc[5]  = fmaf((float)((v.y >> 8) & 255), w, acc[5]);
    acc[6]  = fmaf((float)((v.y >> 16) & 255), w, acc[6]);
    acc[7]  = fmaf((float)(v.y >> 24), w, acc[7]);
    acc[8]  = fmaf((float)(v.z & 255), w, acc[8]);
    acc[9]  = fmaf((float)((v.z >> 8) & 255), w, acc[9]);
    acc[10] = fmaf((float)((v.z >> 16) & 255), w, acc[10]);
    acc[11] = fmaf((float)(v.z >> 24), w, acc[11]);
    acc[12] = fmaf((float)(v.w & 255), w, acc[12]);
    acc[13] = fmaf((float)((v.w >> 8) & 255), w, acc[13]);
    acc[14] = fmaf((float)((v.w >> 16) & 255), w, acc[14]);
    acc[15] = fmaf((float)(v.w >> 24), w, acc[15]);
}

__global__ __launch_bounds__(256) void aggregate_q8_wave(
        const unsigned char* __restrict__ q, const float* __restrict__ dinv,
        const float* __restrict__ gscale,
        const int* __restrict__ start, const int* __restrict__ indeg,
        const float4* __restrict__ edge, int use_w3,
        float* __restrict__ out, int n, int E) {
    int node = blockIdx.x * 4 + (threadIdx.x >> 6);
    if (node >= n) return;
    int lane = threadIdx.x & 63;
    int slot = lane >> 3;      // 0..7
    int sl   = lane & 7;       // covers bytes sl*16..sl*16+15
    float di = dinv[node];
    int s0 = start[node];
    int len = indeg[node];
    if (s0 < 0) s0 = 0;
    if (len < 0) len = 0;
    if (s0 + len > E) len = (E - s0 > 0) ? (E - s0) : 0;

    float acc[16] = {};
    int j = slot;
    for (; j + 8 < len; j += 16) {
        float4 ea = edge[s0 + j];
        float4 eb = edge[s0 + j + 8];
        int sa = __float_as_int(ea.x); float wa = use_w3 ? ea.w : ea.z;
        int sb = __float_as_int(eb.x); float wb = use_w3 ? eb.w : eb.z;
        uint4 va = *(const uint4*)(q + (size_t)sa * 128 + sl * 16);
        uint4 vb = *(const uint4*)(q + (size_t)sb * 128 + sl * 16);
        unpack_fma(acc, va, wa);
        unpack_fma(acc, vb, wb);
    }
    if (j < len) {
        float4 ea = edge[s0 + j];
        int sa = __float_as_int(ea.x);
        float wa = use_w3 ? ea.w : ea.z;
        uint4 va = *(const uint4*)(q + (size_t)sa * 128 + sl * 16);
        unpack_fma(acc, va, wa);
    }
#pragma unroll
    for (int o = 8; o < 64; o <<= 1) {
#pragma unroll
        for (int k = 0; k < 16; ++k) acc[k] += __shfl_xor(acc[k], o);
    }
    if (slot == 0) {
        uint4 vs = *(const uint4*)(q + (size_t)node * 128 + sl * 16);
        unpack_fma(acc, vs, gscale[node] * di * di);   // self loop
        float* op = out + (size_t)node * 128 + sl * 16;
        *(float4*)(op + 0)  = *(float4*)&acc[0];
        *(float4*)(op + 4)  = *(float4*)&acc[4];
        *(float4*)(op + 8)  = *(float4*)&acc[8];
        *(float4*)(op + 12) = *(float4*)&acc[12];
    }
}

// ---------------- BN finalize: 64 partial copies -> per-column scale/shift ----------------
// After: statsP[c] = a (= g/sqrt(var+eps)), statsP[128+c] = bp (= b - mean*a)

__global__ void bn_finalize(float* __restrict__ statsP,
                            const float* __restrict__ g, const float* __restrict__ b,
                            int n) {
    __shared__ float sh[256];
    int t = threadIdx.x;   // 256
    float s = 0.f;
    for (int k = 0; k < 64; ++k) s += statsP[k * 256 + t];
    sh[t] = s;
    __syncthreads();
    if (t < 128) {
        float m  = sh[t] / (float)n;
        float vr = sh[128 + t] / (float)n - m * m;
        float a  = g[t] * (1.0f / sqrtf(vr + 1e-5f));
        statsP[t]       = a;
        statsP[128 + t] = b[t] - m * a;
    }
}

// BN affine (precomputed a,bp) + ReLU + 4-bit fake-quant -> u8
__global__ void bn_apply_quant_u8(const float* __restrict__ x,
                                  const float* __restrict__ ab,
                                  const float* __restrict__ gs,
                                  unsigned char* __restrict__ out, int n) {
    int idx = blockIdx.x * blockDim.x + threadIdx.x;
    if (idx >= n * 128) return;
    int c = idx & 127;
    int r = idx >> 7;
    float v = ab[c] * x[idx] + ab[128 + c];
    v = fmaxf(v, 0.0f);
    float qv = fminf(fmaxf(v / gs[r], 0.0f), 15.0f);
    out[idx] = (unsigned char)rintf(qv);   // round-half-even
}

// ---------------- launch ----------------

extern "C" void kernel_launch(void* const* d_in, const int* in_sizes, int n_in,
                              void* d_out, int out_size, void* d_ws, size_t ws_size,
                              hipStream_t stream) {
    float*       xbuf = (float*)d_in[0];          // reused as scratch after layer-1 agg
    const int*   ei   = (const int*)d_in[1];
    const float* W1   = (const float*)d_in[2];
    const float* b1   = (const float*)d_in[3];
    const float* a1   = (const float*)d_in[4];
    const float* W2   = (const float*)d_in[5];
    const float* b2   = (const float*)d_in[6];
    const float* a2   = (const float*)d_in[7];
    const float* g2   = (const float*)d_in[8];
    const float* W3   = (const float*)d_in[9];
    const float* b3   = (const float*)d_in[10];
    const float* a3   = (const float*)d_in[11];
    const float* g3   = (const float*)d_in[12];
    const float* bn1g = (const float*)d_in[13];
    const float* bn1b = (const float*)d_in[14];
    const float* bn2g = (const float*)d_in[15];
    const float* bn2b = (const float*)d_in[16];

    const int n = in_sizes[0] / 128;      // 50000
    const int E = in_sizes[1] / 2;        // 800000
    const int C = in_sizes[9] / 128;      // 40
    const int* src = ei;
    const int* dst = ei + E;

    // ---- workspace layout: zeroed region FIRST ----
    char* wsp = (char*)d_ws;
    size_t off = 0;
    auto take = [&](size_t bytes) -> void* {
        void* p = wsp + off;
        off += (bytes + 255) & ~(size_t)255;
        return p;
    };
    int*   indeg   = (int*)take((size_t)n * 4);
    int*   counter = (int*)take(4);
    float* stats1  = (float*)take(64 * 256 * 4);     // 64 partial copies: sums|sumsq
    float* stats2  = (float*)take(64 * 256 * 4);
    size_t zeroBytes = off;
    int*   startA  = (int*)take((size_t)n * 4);
    int*   cursor  = (int*)take((size_t)n * 4);
    float* dinv    = (float*)take((size_t)n * 4);
    float* colsumS = (float*)take((size_t)n * 4);
    float4* nodeW  = (float4*)take((size_t)n * 16);
    float4* edge   = (float4*)take((size_t)E * 16);
    float* w1q     = (float*)take(128 * 128 * 4);
    float* w2q     = (float*)take(128 * 128 * 4);
    float* w3q     = (float*)take((size_t)128 * C * 4);
    unsigned char* qbuf = (unsigned char*)take((size_t)n * 128);
    float* hbuf    = (float*)take((size_t)n * 128 * 4);

    float* outF  = (float*)d_out;

    // ---- setup ----
    hipMemsetAsync(d_ws, 0, zeroBytes, stream);
    count_indeg<<<(E + 255) / 256, 256, 0, stream>>>(dst, E, indeg);
    const int nW = 128 * 128 + 128 * 128 + 128 * C;
    int setupN = (n > nW) ? n : nW;
    setup_misc<<<(setupN + 255) / 256, 256, 0, stream>>>(
        indeg, dinv, startA, cursor, counter, g2, g3, nodeW, n,
        W1, a1, W2, a2, W3, a3, w1q, w2q, w3q, 128 * 128, 128 * 128, 128 * C);
    fill_csr_w<<<(E + 255) / 256, 256, 0, stream>>>(src, dst, E, cursor, nodeW, dinv,
                                                    edge, n);

    const int gElem128 = (n * 128 + 255) / 256;
    const int gWave = (n + 3) / 4;
    const int gRow128 = (n + 127) / 128;

    // ---- layer 1: aggregate(x) first (linearity), then GEMM w/ fused rowsum*bias
    //      + fused BN stats ----
    aggregate128_wave<<<gWave, 256, 0, stream>>>(xbuf, dinv, startA, indeg, edge,
                                                 hbuf, colsumS, n, E);
    gemm128_bias<<<gRow128, 256, 0, stream>>>(hbuf, w1q, b1, dinv, colsumS,
                                              xbuf, stats1, n, 128);
    bn_finalize<<<1, 256, 0, stream>>>(stats1, bn1g, bn1b, n);
    bn_apply_quant_u8<<<gElem128, 256, 0, stream>>>(xbuf, stats1, g2, qbuf, n);

    // ---- layer 2: aggregate(q)*W + rowsum*b (stats fused into GEMM) ----
    aggregate_q8_wave<<<gWave, 256, 0, stream>>>(qbuf, dinv, g2, startA, indeg,
                                                 edge, 0, hbuf, n, E);
    gemm128_bias<<<gRow128, 256, 0, stream>>>(hbuf, w2q, b2, dinv, colsumS,
                                              xbuf, stats2, n, 128);
    bn_finalize<<<1, 256, 0, stream>>>(stats2, bn2g, bn2b, n);
    bn_apply_quant_u8<<<gElem128, 256, 0, stream>>>(xbuf, stats2, g3, qbuf, n);

    // ---- layer 3: aggregate(q)*W3 + rowsum*b3, softmax fused ----
    aggregate_q8_wave<<<gWave, 256, 0, stream>>>(qbuf, dinv, g3, startA, indeg,
                                                 edge, 1, hbuf, n, E);
    gemm40_softmax<<<gRow128, 256, 0, stream>>>(hbuf, w3q, b3, dinv, colsumS,
                                                outF, n, C, 128);
}

// Round 8
// 414.725 us; speedup vs baseline: 1.0954x; 1.0474x over previous
//
#include <hip/hip_runtime.h>
#include <hip/hip_bf16.h>
#include <math.h>

// ---------------- graph structure ----------------

__global__ void count_indeg(const int* __restrict__ dst, int e, int* __restrict__ indeg) {
    int i = blockIdx.x * blockDim.x + threadIdx.x;
    if (i < e) atomicAdd(&indeg[dst[i]], 1);
}

// fused setup: dinv + ranges + nodeW table (i < n)  |  weight fake-quant (i < nW)
__global__ void setup_misc(const int* __restrict__ indeg, float* __restrict__ dinv,
                           int* __restrict__ start, int* __restrict__ cursor,
                           int* __restrict__ counter,
                           const float* __restrict__ g2, const float* __restrict__ g3,
                           float4* __restrict__ nodeW, int n,
                           const float* __restrict__ W1, const float* __restrict__ a1,
                           const float* __restrict__ W2, const float* __restrict__ a2,
                           const float* __restrict__ W3, const float* __restrict__ a3,
                           float* __restrict__ w1q, float* __restrict__ w2q,
                           float* __restrict__ w3q, int n1, int n2, int n3) {
    int i = blockIdx.x * blockDim.x + threadIdx.x;
    if (i < n) {
        int d = indeg[i];
        float ds = 1.0f / sqrtf((float)(d + 1));
        dinv[i] = ds;
        nodeW[i] = make_float4(ds, ds * g2[i], ds * g3[i], 0.0f);
        int s = atomicAdd(counter, d);
        start[i] = s;
        cursor[i] = s;
    }
    const float* w; const float* a; float* o; int k;
    if (i < n1) { w = W1; a = a1; o = w1q; k = i; }
    else if (i < n1 + n2) { w = W2; a = a2; o = w2q; k = i - n1; }
    else if (i < n1 + n2 + n3) { w = W3; a = a3; o = w3q; k = i - n1 - n2; }
    else return;
    float s = a[0];
    float v = w[k] / s;
    v = fminf(fmaxf(v, -8.0f), 7.0f);
    o[k] = rintf(v) * s;   // round-half-even, matches jnp.round
}

// CSR fill, AoS edge record: edge[p] = {as_float(src), w0, w1, w2}
// w{0,1,2} = dinv[s]*{1,g2[s],g3[s]}*dinv[d]. ONE scattered 16B store per edge.
// Invalid src -> src = dst (safe row), w = 0: gathers need no validity checks.
__global__ void fill_csr_w(const int* __restrict__ src, const int* __restrict__ dst,
                           int e, int* __restrict__ cursor,
                           const float4* __restrict__ nodeW, const float* __restrict__ dinv,
                           float4* __restrict__ edge, int n) {
    int i = blockIdx.x * blockDim.x + threadIdx.x;
    if (i >= e) return;
    int s = src[i];
    int d = dst[i];
    int p = atomicAdd(&cursor[d], 1);
    if (p < 0 || p >= e) return;
    float dd = dinv[d];
    float4 rec;
    if ((unsigned)s < (unsigned)n) {
        float4 w = nodeW[s];
        rec = make_float4(__int_as_float(s), w.x * dd, w.y * dd, w.z * dd);
    } else {
        rec = make_float4(__int_as_float(d), 0.f, 0.f, 0.f);
    }
    edge[p] = rec;
}

// ---------------- GEMM 128-col + optional fused BN-stats partials ----------------
// C = A@B + rs*bias, rs = di^2 + colsumS[row] (colsumS already includes di factor).

__global__ __launch_bounds__(256) void gemm128_bias(
        const float* __restrict__ A, const float* __restrict__ B,
        const float* __restrict__ bias,
        const float* __restrict__ dinv, const float* __restrict__ colsumS,
        float* __restrict__ C, float* __restrict__ statsP, int M, int K) {
    __shared__ float sA[16][132];
    __shared__ float sB[16][132];
    int tid = threadIdx.x;
    int rowBase = blockIdx.x * 128;
    int tx = tid & 15;
    int ty = tid >> 4;
    float acc[8][8] = {};

    int aRow = tid >> 1;
    int aK   = (tid & 1) * 8;
    int bK   = tid >> 4;
    int bCol = (tid & 15) * 8;

    for (int k0 = 0; k0 < K; k0 += 16) {
        int gRow = rowBase + aRow;
        if (gRow >= M) gRow = M - 1;
        const float* ap = A + (size_t)gRow * K + k0 + aK;
        float4 a0 = *(const float4*)ap;
        float4 a1 = *(const float4*)(ap + 4);
        sA[aK + 0][aRow] = a0.x;
        sA[aK + 1][aRow] = a0.y;
        sA[aK + 2][aRow] = a0.z;
        sA[aK + 3][aRow] = a0.w;
        sA[aK + 4][aRow] = a1.x;
        sA[aK + 5][aRow] = a1.y;
        sA[aK + 6][aRow] = a1.z;
        sA[aK + 7][aRow] = a1.w;
        const float* bp = B + (size_t)(k0 + bK) * 128 + bCol;
        *(float4*)&sB[bK][bCol]     = *(const float4*)bp;
        *(float4*)&sB[bK][bCol + 4] = *(const float4*)(bp + 4);
        __syncthreads();

#pragma unroll
        for (int kk = 0; kk < 16; ++kk) {
            float4 av0 = *(const float4*)&sA[kk][ty * 8];
            float4 av1 = *(const float4*)&sA[kk][ty * 8 + 4];
            float4 bv0 = *(const float4*)&sB[kk][tx * 4];
            float4 bv1 = *(const float4*)&sB[kk][64 + tx * 4];
            float a[8] = {av0.x, av0.y, av0.z, av0.w, av1.x, av1.y, av1.z, av1.w};
            float b[8] = {bv0.x, bv0.y, bv0.z, bv0.w, bv1.x, bv1.y, bv1.z, bv1.w};
#pragma unroll
            for (int i = 0; i < 8; ++i)
#pragma unroll
                for (int j = 0; j < 8; ++j)
                    acc[i][j] = fmaf(a[i], b[j], acc[i][j]);
        }
        __syncthreads();
    }

    int c0 = tx * 4, c1 = 64 + tx * 4;
    float bb[8];
#pragma unroll
    for (int j = 0; j < 4; ++j) { bb[j] = bias[c0 + j]; bb[4 + j] = bias[c1 + j]; }
    float s1[8] = {}, s2[8] = {};
#pragma unroll
    for (int i = 0; i < 8; ++i) {
        int row = rowBase + ty * 8 + i;
        if (row >= M) continue;
        float rs = 1.0f;
        if (dinv) { float di = dinv[row]; rs = di * di + colsumS[row]; }
        float v[8];
#pragma unroll
        for (int j = 0; j < 8; ++j) {
            v[j] = acc[i][j] + rs * bb[j];
            s1[j] += v[j];
            s2[j] += v[j] * v[j];
        }
        *(float4*)&C[(size_t)row * 128 + c0] = *(float4*)&v[0];
        *(float4*)&C[(size_t)row * 128 + c1] = *(float4*)&v[4];
    }
    if (statsP) {
        float* sp = statsP + (blockIdx.x & 63) * 256;
#pragma unroll
        for (int j = 0; j < 4; ++j) { sA[ty][c0 + j] = s1[j]; sA[ty][c1 + j] = s1[4 + j]; }
        __syncthreads();
        if (tid < 128) {
            float t = 0.f;
#pragma unroll
            for (int k = 0; k < 16; ++k) t += sA[k][tid];
            atomicAdd(&sp[tid], t);
        }
        __syncthreads();
#pragma unroll
        for (int j = 0; j < 4; ++j) { sA[ty][c0 + j] = s2[j]; sA[ty][c1 + j] = s2[4 + j]; }
        __syncthreads();
        if (tid < 128) {
            float t = 0.f;
#pragma unroll
            for (int k = 0; k < 16; ++k) t += sA[k][tid];
            atomicAdd(&sp[128 + tid], t);
        }
    }
}

// ---------------- layer-3 GEMM (N<=64) + fused log_softmax ----------------

__global__ __launch_bounds__(256) void gemm40_softmax(
        const float* __restrict__ A, const float* __restrict__ B,
        const float* __restrict__ bias,
        const float* __restrict__ dinv, const float* __restrict__ colsumS,
        float* __restrict__ out, int M, int N, int K) {
    __shared__ float sA[16][132];
    __shared__ float sB[16][68];
    __shared__ float sOut[128][41];
    int tid = threadIdx.x;
    int rowBase = blockIdx.x * 128;
    int tx = tid & 15;
    int ty = tid >> 4;
    float acc[8][4] = {};

    int aRow = tid >> 1;
    int aK   = (tid & 1) * 8;
    int bK   = tid >> 4;
    int bCol = (tid & 15) * 4;

    for (int k0 = 0; k0 < K; k0 += 16) {
        int gRow = rowBase + aRow;
        if (gRow >= M) gRow = M - 1;
        const float* ap = A + (size_t)gRow * K + k0 + aK;
        float4 a0 = *(const float4*)ap;
        float4 a1 = *(const float4*)(ap + 4);
        sA[aK + 0][aRow] = a0.x;
        sA[aK + 1][aRow] = a0.y;
        sA[aK + 2][aRow] = a0.z;
        sA[aK + 3][aRow] = a0.w;
        sA[aK + 4][aRow] = a1.x;
        sA[aK + 5][aRow] = a1.y;
        sA[aK + 6][aRow] = a1.z;
        sA[aK + 7][aRow] = a1.w;
#pragma unroll
        for (int j = 0; j < 4; ++j) {
            int col = bCol + j;
            sB[bK][col] = (col < N) ? B[(size_t)(k0 + bK) * N + col] : 0.0f;
        }
        __syncthreads();
#pragma unroll
        for (int kk = 0; kk < 16; ++kk) {
            float4 av0 = *(const float4*)&sA[kk][ty * 8];
            float4 av1 = *(const float4*)&sA[kk][ty * 8 + 4];
            float4 bv  = *(const float4*)&sB[kk][tx * 4];
            float a[8] = {av0.x, av0.y, av0.z, av0.w, av1.x, av1.y, av1.z, av1.w};
            float b[4] = {bv.x, bv.y, bv.z, bv.w};
#pragma unroll
            for (int i = 0; i < 8; ++i)
#pragma unroll
                for (int j = 0; j < 4; ++j)
                    acc[i][j] = fmaf(a[i], b[j], acc[i][j]);
        }
        __syncthreads();
    }

    int colOut = tx * 4;
    float bb[4];
#pragma unroll
    for (int j = 0; j < 4; ++j) bb[j] = (colOut + j < N) ? bias[colOut + j] : 0.0f;
#pragma unroll
    for (int i = 0; i < 8; ++i) {
        int rowL = ty * 8 + i;
        int row = rowBase + rowL;
        float rs = 1.0f;
        if (row < M) { float di = dinv[row]; rs = di * di + colsumS[row]; }
#pragma unroll
        for (int j = 0; j < 4; ++j)
            if (colOut + j < N) sOut[rowL][colOut + j] = acc[i][j] + rs * bb[j];
    }
    __syncthreads();
    if (tid < 128) {
        int row = rowBase + tid;
        if (row < M) {
            float mx = -INFINITY;
            for (int c = 0; c < N; ++c) mx = fmaxf(mx, sOut[tid][c]);
            float sm = 0.f;
            for (int c = 0; c < N; ++c) sm += expf(sOut[tid][c] - mx);
            float lg = mx + logf(sm);
            float* op = out + (size_t)row * N;
            for (int c = 0; c < N; ++c) op[c] = sOut[tid][c] - lg;
        }
    }
}

// ---------------- fp32 aggregation (layer 1): one WAVE per node ----------------
// 2 slots x 32 lanes; 6 rows in flight per slot (12 edges/iter) to cover
// HBM/L2 latency. Edge record read as float2 {src, w0} (8B of the 16B AoS rec).
// colsumS[node] = sum edge.y (coalesced pre-pass, also warms L2).

__device__ __forceinline__ void fma4(float4& acc, float4 v, float s) {
    acc.x = fmaf(v.x, s, acc.x);
    acc.y = fmaf(v.y, s, acc.y);
    acc.z = fmaf(v.z, s, acc.z);
    acc.w = fmaf(v.w, s, acc.w);
}

__global__ __launch_bounds__(256) void aggregate128_wave(
        const float* __restrict__ h, const float* __restrict__ dinv,
        const int* __restrict__ start, const int* __restrict__ indeg,
        const float4* __restrict__ edge,
        float* __restrict__ out, float* __restrict__ colsumS, int n, int E) {
    int node = blockIdx.x * 4 + (threadIdx.x >> 6);
    if (node >= n) return;
    int lane = threadIdx.x & 63;
    int slot = lane >> 5;       // 0..1
    int c4 = (lane & 31) * 4;   // column (floats)
    float di = dinv[node];
    int s0 = start[node];
    int len = indeg[node];
    if (s0 < 0) s0 = 0;
    if (len < 0) len = 0;
    if (s0 + len > E) len = (E - s0 > 0) ? (E - s0) : 0;

    // self-loop row load issued early
    float4 hs = *(const float4*)(h + (size_t)node * 128 + c4);

    // colsum partial: coalesced, each edge once (also prefetches edge lines)
    float wacc = 0.f;
    for (int t = lane; t < len; t += 64) wacc += edge[s0 + t].y;

    const float2* e2 = (const float2*)edge;   // record i -> e2[2*i] = {src, w0}

    float4 acc = {0.f, 0.f, 0.f, 0.f};
    int j = slot;
    // 6 rows in flight per slot
    for (; j + 10 < len; j += 12) {
        float2 ea = e2[(size_t)(s0 + j) * 2];
        float2 eb = e2[(size_t)(s0 + j + 2) * 2];
        float2 ec = e2[(size_t)(s0 + j + 4) * 2];
        float2 ed = e2[(size_t)(s0 + j + 6) * 2];
        float2 ee = e2[(size_t)(s0 + j + 8) * 2];
        float2 ef = e2[(size_t)(s0 + j + 10) * 2];
        float4 va = *(const float4*)(h + (size_t)__float_as_int(ea.x) * 128 + c4);
        float4 vb = *(const float4*)(h + (size_t)__float_as_int(eb.x) * 128 + c4);
        float4 vc = *(const float4*)(h + (size_t)__float_as_int(ec.x) * 128 + c4);
        float4 vd = *(const float4*)(h + (size_t)__float_as_int(ed.x) * 128 + c4);
        float4 ve = *(const float4*)(h + (size_t)__float_as_int(ee.x) * 128 + c4);
        float4 vf = *(const float4*)(h + (size_t)__float_as_int(ef.x) * 128 + c4);
        fma4(acc, va, ea.y);
        fma4(acc, vb, eb.y);
        fma4(acc, vc, ec.y);
        fma4(acc, vd, ed.y);
        fma4(acc, ve, ee.y);
        fma4(acc, vf, ef.y);
    }
    // 2 rows in flight
    for (; j + 2 < len; j += 4) {
        float2 ea = e2[(size_t)(s0 + j) * 2];
        float2 eb = e2[(size_t)(s0 + j + 2) * 2];
        float4 va = *(const float4*)(h + (size_t)__float_as_int(ea.x) * 128 + c4);
        float4 vb = *(const float4*)(h + (size_t)__float_as_int(eb.x) * 128 + c4);
        fma4(acc, va, ea.y);
        fma4(acc, vb, eb.y);
    }
    // 1 row
    for (; j < len; j += 2) {
        float2 ea = e2[(size_t)(s0 + j) * 2];
        float4 va = *(const float4*)(h + (size_t)__float_as_int(ea.x) * 128 + c4);
        fma4(acc, va, ea.y);
    }
#pragma unroll
    for (int o = 1; o < 64; o <<= 1) wacc += __shfl_xor(wacc, o);
    acc.x += __shfl_xor(acc.x, 32);
    acc.y += __shfl_xor(acc.y, 32);
    acc.z += __shfl_xor(acc.z, 32);
    acc.w += __shfl_xor(acc.w, 32);
    if (lane < 32) {
        float dd = di * di;
        acc.x = fmaf(hs.x, dd, acc.x);
        acc.y = fmaf(hs.y, dd, acc.y);
        acc.z = fmaf(hs.z, dd, acc.z);
        acc.w = fmaf(hs.w, dd, acc.w);
        *(float4*)(out + (size_t)node * 128 + c4) = acc;
        if (lane == 0) colsumS[node] = wacc;
    }
}

// ---------------- u8 aggregation (layers 2,3): one WAVE per node ----------------
// 4 slots x 16 lanes (uint2 = 8B/lane); 4 rows in flight per slot so the
// common degree~16 node is fully covered in one iteration.
// Weight from edge record (z = layer2, w = layer3).

__device__ __forceinline__ void unpack_fma8(float* acc, uint2 v, float s) {
    acc[0] = fmaf((float)(v.x & 255), s, acc[0]);
    acc[1] = fmaf((float)((v.x >> 8) & 255), s, acc[1]);
    acc[2] = fmaf((float)((v.x >> 16) & 255), s, acc[2]);
    acc[3] = fmaf((float)(v.x >> 24), s, acc[3]);
    acc[4] = fmaf((float)(v.y & 255), s, acc[4]);
    acc[5] = fmaf((float)((v.y >> 8) & 255), s, acc[5]);
    acc[6] = fmaf((float)((v.y >> 16) & 255), s, acc[6]);
    acc[7] = fmaf((float)(v.y >> 24), s, acc[7]);
}

__global__ __launch_bounds__(256) void aggregate_q8_wave(
        const unsigned char* __restrict__ q, const float* __restrict__ dinv,
        const float* __restrict__ gscale,
        const int* __restrict__ start, const int* __restrict__ indeg,
        const float4* __restrict__ edge, int use_w3,
        float* __restrict__ out, int n, int E) {
    int node = blockIdx.x * 4 + (threadIdx.x >> 6);
    if (node >= n) return;
    int lane = threadIdx.x & 63;
    int slot = lane >> 4;      // 0..3
    int sl   = lane & 15;      // covers bytes sl*8..sl*8+7
    float di = dinv[node];
    int s0 = start[node];
    int len = indeg[node];
    if (s0 < 0) s0 = 0;
    if (len < 0) len = 0;
    if (s0 + len > E) len = (E - s0 > 0) ? (E - s0) : 0;

    float acc[8] = {};
    int j = slot;
    // 4 rows in flight per slot
    for (; j + 12 < len; j += 16) {
        float4 ea = edge[s0 + j];
        float4 eb = edge[s0 + j + 4];
        float4 ec = edge[s0 + j + 8];
        float4 ed = edge[s0 + j + 12];
        int sa = __float_as_int(ea.x); float wa = use_w3 ? ea.w : ea.z;
        int sb = __float_as_int(eb.x); float wb = use_w3 ? eb.w : eb.z;
        int sc = __float_as_int(ec.x); float wc = use_w3 ? ec.w : ec.z;
        int sd = __float_as_int(ed.x); float wd = use_w3 ? ed.w : ed.z;
        uint2 va = *(const uint2*)(q + (size_t)sa * 128 + sl * 8);
        uint2 vb = *(const uint2*)(q + (size_t)sb * 128 + sl * 8);
        uint2 vc = *(const uint2*)(q + (size_t)sc * 128 + sl * 8);
        uint2 vd = *(const uint2*)(q + (size_t)sd * 128 + sl * 8);
        unpack_fma8(acc, va, wa);
        unpack_fma8(acc, vb, wb);
        unpack_fma8(acc, vc, wc);
        unpack_fma8(acc, vd, wd);
    }
    // 1 row
    for (; j < len; j += 4) {
        float4 ea = edge[s0 + j];
        int sa = __float_as_int(ea.x);
        float wa = use_w3 ? ea.w : ea.z;
        uint2 va = *(const uint2*)(q + (size_t)sa * 128 + sl * 8);
        unpack_fma8(acc, va, wa);
    }
#pragma unroll
    for (int o = 16; o < 64; o <<= 1) {
#pragma unroll
        for (int k = 0; k < 8; ++k) acc[k] += __shfl_xor(acc[k], o);
    }
    if (slot == 0) {
        uint2 vs = *(const uint2*)(q + (size_t)node * 128 + sl * 8);
        unpack_fma8(acc, vs, gscale[node] * di * di);   // self loop
        float* op = out + (size_t)node * 128 + sl * 8;
        *(float4*)(op + 0) = make_float4(acc[0], acc[1], acc[2], acc[3]);
        *(float4*)(op + 4) = make_float4(acc[4], acc[5], acc[6], acc[7]);
    }
}

// ---------------- BN finalize: 64 partial copies -> per-column scale/shift ----------------
// After: statsP[c] = a (= g/sqrt(var+eps)), statsP[128+c] = bp (= b - mean*a)

__global__ void bn_finalize(float* __restrict__ statsP,
                            const float* __restrict__ g, const float* __restrict__ b,
                            int n) {
    __shared__ float sh[256];
    int t = threadIdx.x;   // 256
    float s = 0.f;
    for (int k = 0; k < 64; ++k) s += statsP[k * 256 + t];
    sh[t] = s;
    __syncthreads();
    if (t < 128) {
        float m  = sh[t] / (float)n;
        float vr = sh[128 + t] / (float)n - m * m;
        float a  = g[t] * (1.0f / sqrtf(vr + 1e-5f));
        statsP[t]       = a;
        statsP[128 + t] = b[t] - m * a;
    }
}

// BN affine (precomputed a,bp) + ReLU + 4-bit fake-quant -> u8, 4 elems/thread
__global__ void bn_apply_quant_u8(const float* __restrict__ x,
                                  const float* __restrict__ ab,
                                  const float* __restrict__ gs,
                                  uchar4* __restrict__ out, int n) {
    int i = blockIdx.x * blockDim.x + threadIdx.x;   // over n*32
    if (i >= n * 32) return;
    int r = i >> 5;
    int c = (i & 31) * 4;
    float4 xv = *(const float4*)(x + (size_t)i * 4);
    float g = gs[r];
    float a0 = ab[c + 0], a1 = ab[c + 1], a2 = ab[c + 2], a3 = ab[c + 3];
    float p0 = ab[128 + c + 0], p1 = ab[128 + c + 1], p2 = ab[128 + c + 2], p3 = ab[128 + c + 3];
    float v0 = fmaxf(a0 * xv.x + p0, 0.0f);
    float v1 = fmaxf(a1 * xv.y + p1, 0.0f);
    float v2 = fmaxf(a2 * xv.z + p2, 0.0f);
    float v3 = fmaxf(a3 * xv.w + p3, 0.0f);
    uchar4 o;
    o.x = (unsigned char)rintf(fminf(fmaxf(v0 / g, 0.0f), 15.0f));
    o.y = (unsigned char)rintf(fminf(fmaxf(v1 / g, 0.0f), 15.0f));
    o.z = (unsigned char)rintf(fminf(fmaxf(v2 / g, 0.0f), 15.0f));
    o.w = (unsigned char)rintf(fminf(fmaxf(v3 / g, 0.0f), 15.0f));
    out[i] = o;
}

// ---------------- launch ----------------

extern "C" void kernel_launch(void* const* d_in, const int* in_sizes, int n_in,
                              void* d_out, int out_size, void* d_ws, size_t ws_size,
                              hipStream_t stream) {
    float*       xbuf = (float*)d_in[0];          // reused as scratch after layer-1 agg
    const int*   ei   = (const int*)d_in[1];
    const float* W1   = (const float*)d_in[2];
    const float* b1   = (const float*)d_in[3];
    const float* a1   = (const float*)d_in[4];
    const float* W2   = (const float*)d_in[5];
    const float* b2   = (const float*)d_in[6];
    const float* a2   = (const float*)d_in[7];
    const float* g2   = (const float*)d_in[8];
    const float* W3   = (const float*)d_in[9];
    const float* b3   = (const float*)d_in[10];
    const float* a3   = (const float*)d_in[11];
    const float* g3   = (const float*)d_in[12];
    const float* bn1g = (const float*)d_in[13];
    const float* bn1b = (const float*)d_in[14];
    const float* bn2g = (const float*)d_in[15];
    const float* bn2b = (const float*)d_in[16];

    const int n = in_sizes[0] / 128;      // 50000
    const int E = in_sizes[1] / 2;        // 800000
    const int C = in_sizes[9] / 128;      // 40
    const int* src = ei;
    const int* dst = ei + E;

    // ---- workspace layout: zeroed region FIRST ----
    char* wsp = (char*)d_ws;
    size_t off = 0;
    auto take = [&](size_t bytes) -> void* {
        void* p = wsp + off;
        off += (bytes + 255) & ~(size_t)255;
        return p;
    };
    int*   indeg   = (int*)take((size_t)n * 4);
    int*   counter = (int*)take(4);
    float* stats1  = (float*)take(64 * 256 * 4);     // 64 partial copies: sums|sumsq
    float* stats2  = (float*)take(64 * 256 * 4);
    size_t zeroBytes = off;
    int*   startA  = (int*)take((size_t)n * 4);
    int*   cursor  = (int*)take((size_t)n * 4);
    float* dinv    = (float*)take((size_t)n * 4);
    float* colsumS = (float*)take((size_t)n * 4);
    float4* nodeW  = (float4*)take((size_t)n * 16);
    float4* edge   = (float4*)take((size_t)E * 16);
    float* w1q     = (float*)take(128 * 128 * 4);
    float* w2q     = (float*)take(128 * 128 * 4);
    float* w3q     = (float*)take((size_t)128 * C * 4);
    unsigned char* qbuf = (unsigned char*)take((size_t)n * 128);
    float* hbuf    = (float*)take((size_t)n * 128 * 4);

    float* outF  = (float*)d_out;

    // ---- setup ----
    hipMemsetAsync(d_ws, 0, zeroBytes, stream);
    count_indeg<<<(E + 255) / 256, 256, 0, stream>>>(dst, E, indeg);
    const int nW = 128 * 128 + 128 * 128 + 128 * C;
    int setupN = (n > nW) ? n : nW;
    setup_misc<<<(setupN + 255) / 256, 256, 0, stream>>>(
        indeg, dinv, startA, cursor, counter, g2, g3, nodeW, n,
        W1, a1, W2, a2, W3, a3, w1q, w2q, w3q, 128 * 128, 128 * 128, 128 * C);
    fill_csr_w<<<(E + 255) / 256, 256, 0, stream>>>(src, dst, E, cursor, nodeW, dinv,
                                                    edge, n);

    const int gElem32 = (n * 32 + 255) / 256;
    const int gWave = (n + 3) / 4;
    const int gRow128 = (n + 127) / 128;

    // ---- layer 1: aggregate(x) first (linearity), then GEMM w/ fused rowsum*bias
    //      + fused BN stats ----
    aggregate128_wave<<<gWave, 256, 0, stream>>>(xbuf, dinv, startA, indeg, edge,
                                                 hbuf, colsumS, n, E);
    gemm128_bias<<<gRow128, 256, 0, stream>>>(hbuf, w1q, b1, dinv, colsumS,
                                              xbuf, stats1, n, 128);
    bn_finalize<<<1, 256, 0, stream>>>(stats1, bn1g, bn1b, n);
    bn_apply_quant_u8<<<gElem32, 256, 0, stream>>>(xbuf, stats1, g2, (uchar4*)qbuf, n);

    // ---- layer 2: aggregate(q)*W + rowsum*b (stats fused into GEMM) ----
    aggregate_q8_wave<<<gWave, 256, 0, stream>>>(qbuf, dinv, g2, startA, indeg,
                                                 edge, 0, hbuf, n, E);
    gemm128_bias<<<gRow128, 256, 0, stream>>>(hbuf, w2q, b2, dinv, colsumS,
                                              xbuf, stats2, n, 128);
    bn_finalize<<<1, 256, 0, stream>>>(stats2, bn2g, bn2b, n);
    bn_apply_quant_u8<<<gElem32, 256, 0, stream>>>(xbuf, stats2, g3, (uchar4*)qbuf, n);

    // ---- layer 3: aggregate(q)*W3 + rowsum*b3, softmax fused ----
    aggregate_q8_wave<<<gWave, 256, 0, stream>>>(qbuf, dinv, g3, startA, indeg,
                                                 edge, 1, hbuf, n, E);
    gemm40_softmax<<<gRow128, 256, 0, stream>>>(hbuf, w3q, b3, dinv, colsumS,
                                                outF, n, C, 128);
}